// Round 5
// baseline (123.896 us; speedup 1.0000x reference)
//
#include <hip/hip_runtime.h>

#define N_EDGES 4096
#define HIDDEN  256
#define EDGE_DIM 128
#define NUM_HEADS 4
#define NUM_GRAPHS 64
#define DH 64   // head dim

typedef __attribute__((ext_vector_type(8))) short short8;
typedef __attribute__((ext_vector_type(4))) float f32x4;

__device__ __forceinline__ unsigned short f2bf(float f) {
  unsigned u = __builtin_bit_cast(unsigned, f);
  u += 0x7FFF + ((u >> 16) & 1);          // RNE
  return (unsigned short)(u >> 16);
}
__device__ __forceinline__ float bf2f(unsigned short u) {
  return __builtin_bit_cast(float, (unsigned)u << 16);
}
__device__ __forceinline__ short8 cvt8(float4 x, float4 y) {
  short8 v;
  v[0] = (short)f2bf(x.x); v[1] = (short)f2bf(x.y);
  v[2] = (short)f2bf(x.z); v[3] = (short)f2bf(x.w);
  v[4] = (short)f2bf(y.x); v[5] = (short)f2bf(y.y);
  v[6] = (short)f2bf(y.z); v[7] = (short)f2bf(y.w);
  return v;
}
__device__ __forceinline__ float4 us4f(ushort4 v) {
  float4 f;
  f.x = bf2f(v.x); f.y = bf2f(v.y); f.z = bf2f(v.z); f.w = bf2f(v.w);
  return f;
}

__device__ __forceinline__ int lbound(const int* __restrict__ a, int n, int v) {
  int lo = 0, hi = n;
  while (lo < hi) { int mid = (lo + hi) >> 1; if (a[mid] < v) lo = mid + 1; else hi = mid; }
  return lo;
}

// MFMA GEMM tile: 64x64 out, 256 thr = 4 waves, BK=64 (round-4-proven).
// A fp32/bf16 [M x K]; W fp32/bf16 [N x K] row-major.
// OUTF32: C = fp32(acc+bias+res) stride HIDDEN; else C = bf16(acc+bias).
template<bool ABF, bool WBF, bool OUTF32>
__device__ __forceinline__ void gemm_tile(const void* Ap, const void* Wp,
                                          const float* __restrict__ bias,
                                          const float* __restrict__ res,
                                          void* Cp, const int K,
                                          const int m0, const int n0,
                                          unsigned short* As, unsigned short* Ws) {
  const int t = threadIdx.x;
  const int r = t >> 2, kg = t & 3;           // row 0..63, 16-elem k-group 0..3
  const int lane = t & 63, w = t >> 6;
  const int quad = lane >> 4, l16 = lane & 15;
  const int wm = (w >> 1) * 32, wn = (w & 1) * 32;
  f32x4 acc[2][2] = {};
  const float*          pa32 = (const float*)Ap          + (size_t)(m0 + r) * K + kg * 16;
  const unsigned short* pa16 = (const unsigned short*)Ap + (size_t)(m0 + r) * K + kg * 16;
  const float*          pw32 = (const float*)Wp          + (size_t)(n0 + r) * K + kg * 16;
  const unsigned short* pw16 = (const unsigned short*)Wp + (size_t)(n0 + r) * K + kg * 16;
  float4 a0, a1, a2, a3, w0, w1, w2, w3;
  short8 a16a, a16b, w16a, w16b;
  if (ABF) { a16a = *(const short8*)pa16; a16b = *(const short8*)(pa16 + 8); }
  else { a0 = *(const float4*)pa32;       a1 = *(const float4*)(pa32 + 4);
         a2 = *(const float4*)(pa32 + 8); a3 = *(const float4*)(pa32 + 12); }
  if (WBF) { w16a = *(const short8*)pw16; w16b = *(const short8*)(pw16 + 8); }
  else { w0 = *(const float4*)pw32;       w1 = *(const float4*)(pw32 + 4);
         w2 = *(const float4*)(pw32 + 8); w3 = *(const float4*)(pw32 + 12); }
  for (int kc = 0; kc < K; kc += 64) {
    short8 na16a, na16b, nw16a, nw16b;
    float4 na0, na1, na2, na3, nw0, nw1, nw2, nw3;
    if (kc + 64 < K) {
      if (ABF) { na16a = *(const short8*)(pa16 + kc + 64);
                 na16b = *(const short8*)(pa16 + kc + 72); }
      else { na0 = *(const float4*)(pa32 + kc + 64); na1 = *(const float4*)(pa32 + kc + 68);
             na2 = *(const float4*)(pa32 + kc + 72); na3 = *(const float4*)(pa32 + kc + 76); }
      if (WBF) { nw16a = *(const short8*)(pw16 + kc + 64);
                 nw16b = *(const short8*)(pw16 + kc + 72); }
      else { nw0 = *(const float4*)(pw32 + kc + 64); nw1 = *(const float4*)(pw32 + kc + 68);
             nw2 = *(const float4*)(pw32 + kc + 72); nw3 = *(const float4*)(pw32 + kc + 76); }
    }
    __syncthreads();
    *(short8*)&As[r * 72 + kg * 16]     = ABF ? a16a : cvt8(a0, a1);
    *(short8*)&As[r * 72 + kg * 16 + 8] = ABF ? a16b : cvt8(a2, a3);
    *(short8*)&Ws[r * 72 + kg * 16]     = WBF ? w16a : cvt8(w0, w1);
    *(short8*)&Ws[r * 72 + kg * 16 + 8] = WBF ? w16b : cvt8(w2, w3);
    __syncthreads();
#pragma unroll
    for (int ks = 0; ks < 2; ++ks) {
      short8 af0 = *(const short8*)&As[(wm + l16) * 72 + ks * 32 + quad * 8];
      short8 af1 = *(const short8*)&As[(wm + 16 + l16) * 72 + ks * 32 + quad * 8];
      short8 bq0 = *(const short8*)&Ws[(wn + l16) * 72 + ks * 32 + quad * 8];
      short8 bq1 = *(const short8*)&Ws[(wn + 16 + l16) * 72 + ks * 32 + quad * 8];
      acc[0][0] = __builtin_amdgcn_mfma_f32_16x16x32_bf16(af0, bq0, acc[0][0], 0, 0, 0);
      acc[0][1] = __builtin_amdgcn_mfma_f32_16x16x32_bf16(af0, bq1, acc[0][1], 0, 0, 0);
      acc[1][0] = __builtin_amdgcn_mfma_f32_16x16x32_bf16(af1, bq0, acc[1][0], 0, 0, 0);
      acc[1][1] = __builtin_amdgcn_mfma_f32_16x16x32_bf16(af1, bq1, acc[1][1], 0, 0, 0);
    }
    a16a = na16a; a16b = na16b; a0 = na0; a1 = na1; a2 = na2; a3 = na3;
    w16a = nw16a; w16b = nw16b; w0 = nw0; w1 = nw1; w2 = nw2; w3 = nw3;
  }
#pragma unroll
  for (int j = 0; j < 2; ++j) {
    const int col = n0 + wn + j * 16 + l16;
    const float bj = bias[col];
#pragma unroll
    for (int i = 0; i < 2; ++i)
#pragma unroll
      for (int reg = 0; reg < 4; ++reg) {
        const int row = m0 + wm + i * 16 + quad * 4 + reg;
        const size_t idx = (size_t)row * HIDDEN + col;
        float v = acc[i][j][reg] + bj;
        if (OUTF32) ((float*)Cp)[idx] = v + res[idx];
        else        ((unsigned short*)Cp)[idx] = f2bf(v);
      }
  }
}

// LDS union for the fused L1 kernel.
union SharedL1 {
  struct { unsigned short As[64 * 72]; unsigned short Ws[64 * 72]; } g;      // Q path
  struct { unsigned short EkS[64 * 264];                                     // Ek tile bf16
           unsigned short As[64 * 40];                                       // X staging
           unsigned short Ws[256 * 40]; } f;                                 // weight staging
};

// Fused K/V projection for 64 edge-rows, full 256 output cols, one block:
//   EkS = bf16(X[m0:m0+64] @ w_edge^T + b_edge)   (stage 1, LDS resident)
//   Out[m0:m0+64] = bf16(EkS @ Wp^T + bp)          (stage 2)
// 4 waves; wave w owns output cols [w*64, w*64+64) as 4x4 16x16 MFMA tiles.
// Numerics identical to round-0's Ek-bf16-roundtrip path (verified absmax).
__device__ __forceinline__ void fused_kv(const float* __restrict__ X,
                                         const float* __restrict__ w_edge,
                                         const float* __restrict__ b_edge,
                                         const float* __restrict__ Wp,
                                         const float* __restrict__ bp,
                                         unsigned short* __restrict__ Out,
                                         const int m0, SharedL1& sh) {
  const int t = threadIdx.x;
  const int r = t >> 2, kg = t & 3;
  const int lane = t & 63, w = t >> 6;
  const int quad = lane >> 4, l16 = lane & 15;
  unsigned short* EkS = sh.f.EkS;
  unsigned short* As  = sh.f.As;
  unsigned short* Ws  = sh.f.Ws;
  f32x4 acc[4][4] = {};

  // ---- stage 1: Ek = X @ w_edge^T + b_edge ----
  const float* px = X + (size_t)(m0 + r) * EDGE_DIM + kg * 8;   // A: row r, 8 k
  const float* pw = w_edge + (size_t)t * EDGE_DIM;              // B: row n=t
  float4 xa0 = *(const float4*)px, xa1 = *(const float4*)(px + 4);
  float4 wb[8];
#pragma unroll
  for (int i = 0; i < 8; ++i) wb[i] = *(const float4*)(pw + i * 4);
  for (int kc = 0; kc < EDGE_DIM; kc += 32) {
    float4 nxa0, nxa1, nwb[8];
    if (kc + 32 < EDGE_DIM) {
      nxa0 = *(const float4*)(px + kc + 32); nxa1 = *(const float4*)(px + kc + 36);
#pragma unroll
      for (int i = 0; i < 8; ++i) nwb[i] = *(const float4*)(pw + kc + 32 + i * 4);
    }
    __syncthreads();
    *(short8*)&As[r * 40 + kg * 8] = cvt8(xa0, xa1);
#pragma unroll
    for (int i = 0; i < 4; ++i)
      *(short8*)&Ws[t * 40 + i * 8] = cvt8(wb[2 * i], wb[2 * i + 1]);
    __syncthreads();
    short8 af[4], bf[4];
#pragma unroll
    for (int rt = 0; rt < 4; ++rt)
      af[rt] = *(const short8*)&As[(rt * 16 + l16) * 40 + quad * 8];
#pragma unroll
    for (int ct = 0; ct < 4; ++ct)
      bf[ct] = *(const short8*)&Ws[(w * 64 + ct * 16 + l16) * 40 + quad * 8];
#pragma unroll
    for (int rt = 0; rt < 4; ++rt)
#pragma unroll
      for (int ct = 0; ct < 4; ++ct)
        acc[rt][ct] = __builtin_amdgcn_mfma_f32_16x16x32_bf16(af[rt], bf[ct],
                                                              acc[rt][ct], 0, 0, 0);
    xa0 = nxa0; xa1 = nxa1;
#pragma unroll
    for (int i = 0; i < 8; ++i) wb[i] = nwb[i];
  }
  // bias + bf16 round -> EkS; zero acc for stage 2
#pragma unroll
  for (int ct = 0; ct < 4; ++ct) {
    const int col = w * 64 + ct * 16 + l16;
    const float bj = b_edge[col];
#pragma unroll
    for (int rt = 0; rt < 4; ++rt)
#pragma unroll
      for (int reg = 0; reg < 4; ++reg) {
        EkS[(rt * 16 + quad * 4 + reg) * 264 + col] = f2bf(acc[rt][ct][reg] + bj);
        acc[rt][ct][reg] = 0.f;
      }
  }

  // ---- stage 2: Out = EkS @ Wp^T + bp ----
  const float* pw2 = Wp + (size_t)t * HIDDEN;                   // B: row n=t
#pragma unroll
  for (int i = 0; i < 8; ++i) wb[i] = *(const float4*)(pw2 + i * 4);
  for (int kc = 0; kc < HIDDEN; kc += 32) {
    float4 nwb[8];
    if (kc + 32 < HIDDEN)
#pragma unroll
      for (int i = 0; i < 8; ++i) nwb[i] = *(const float4*)(pw2 + kc + 32 + i * 4);
    __syncthreads();   // first iter: EkS writes visible; later: prev Ws reads done
#pragma unroll
    for (int i = 0; i < 4; ++i)
      *(short8*)&Ws[t * 40 + i * 8] = cvt8(wb[2 * i], wb[2 * i + 1]);
    __syncthreads();
    short8 af[4], bf[4];
#pragma unroll
    for (int rt = 0; rt < 4; ++rt)
      af[rt] = *(const short8*)&EkS[(rt * 16 + l16) * 264 + kc + quad * 8];
#pragma unroll
    for (int ct = 0; ct < 4; ++ct)
      bf[ct] = *(const short8*)&Ws[(w * 64 + ct * 16 + l16) * 40 + quad * 8];
#pragma unroll
    for (int rt = 0; rt < 4; ++rt)
#pragma unroll
      for (int ct = 0; ct < 4; ++ct)
        acc[rt][ct] = __builtin_amdgcn_mfma_f32_16x16x32_bf16(af[rt], bf[ct],
                                                              acc[rt][ct], 0, 0, 0);
#pragma unroll
    for (int i = 0; i < 8; ++i) wb[i] = nwb[i];
  }
#pragma unroll
  for (int ct = 0; ct < 4; ++ct) {
    const int col = w * 64 + ct * 16 + l16;
    const float bj = bp[col];
#pragma unroll
    for (int rt = 0; rt < 4; ++rt)
#pragma unroll
      for (int reg = 0; reg < 4; ++reg)
        Out[(size_t)(m0 + rt * 16 + quad * 4 + reg) * HIDDEN + col] =
            f2bf(acc[rt][ct][reg] + bj);
  }
}

// Launch 1: x<64 Kh rows (fused double-GEMM); x<128 Vh rows; x<384 Qh tiles;
// x==384 segStart. Heavy blocks first (dispatch order => wall = heavy time).
__global__ __launch_bounds__(256) void k_qkv(const float* __restrict__ query,
                                             const float* __restrict__ key,
                                             const float* __restrict__ value,
                                             const float* __restrict__ w_in,
                                             const float* __restrict__ b_in,
                                             const float* __restrict__ w_edge,
                                             const float* __restrict__ b_edge,
                                             const int* __restrict__ gidx,
                                             unsigned short* Qh, unsigned short* Kh,
                                             unsigned short* Vh, int* segStart) {
  __shared__ SharedL1 sh;
  const int b = blockIdx.x;
  if (b < 64) {
    fused_kv(key, w_edge, b_edge, w_in + (size_t)256 * HIDDEN, b_in + 256,
             Kh, b * 64, sh);
  } else if (b < 128) {
    fused_kv(value, w_edge, b_edge, w_in + (size_t)512 * HIDDEN, b_in + 512,
             Vh, (b - 64) * 64, sh);
  } else if (b < 384) {
    const int q = b - 128;
    gemm_tile<false, false, false>(query, w_in, b_in, nullptr, Qh, 256,
                                   (q & 63) * 64, (q >> 6) * 64, sh.g.As, sh.g.Ws);
  } else if (threadIdx.x <= NUM_GRAPHS) {
    segStart[threadIdx.x] = lbound(gidx, N_EDGES, threadIdx.x);
  }
}

// Launch 2: segment attention, per-head blocks (round-0-proven structure).
__global__ __launch_bounds__(256) void attn_segment(const unsigned short* __restrict__ Qh,
                                                    const unsigned short* __restrict__ Kh,
                                                    const unsigned short* __restrict__ Vh,
                                                    const int* __restrict__ segStart,
                                                    unsigned short* __restrict__ ao) {
  const int graph = blockIdx.x, h = blockIdx.y, zg = blockIdx.z;
  const int segLo = segStart[graph];
  const int segHi = segStart[graph + 1];
  const int segLen = segHi - segLo;
  const int t = threadIdx.x, lane = t & 63, w = t >> 6;
  __shared__ float Qs[16][68], Ks[64][68], Vs[64][68];
  __shared__ float Ps[4][64][4];
  const float scale = 0.125f;           // 1/sqrt(64)
  const int r0 = w * 4;

  for (int chunk = zg; chunk * 16 < segLen; chunk += 8) {
    const int row0 = segLo + chunk * 16;
    const int rows = min(16, segHi - row0);
    __syncthreads();                    // prev chunk fully consumed
    { int r = t >> 4, d4 = (t & 15) * 4;
      if (r < rows)
        *(float4*)&Qs[r][d4] =
            us4f(*(const ushort4*)(Qh + (size_t)(row0 + r) * HIDDEN + h * DH + d4)); }

    float accv[4] = {0.f, 0.f, 0.f, 0.f}, lsum[4] = {0.f, 0.f, 0.f, 0.f};

    for (int c0 = segLo; c0 < segHi; c0 += 64) {
      const int tc = min(64, segHi - c0);
      __syncthreads();                  // Qs staged / prev tile reads done
#pragma unroll
      for (int it = 0; it < 4; ++it) {
        int s = t + it * 256; int j = s >> 4; int d4 = (s & 15) * 4;
        if (j < tc) {
          *(float4*)&Ks[j][d4] =
              us4f(*(const ushort4*)(Kh + (size_t)(c0 + j) * HIDDEN + h * DH + d4));
          *(float4*)&Vs[j][d4] =
              us4f(*(const ushort4*)(Vh + (size_t)(c0 + j) * HIDDEN + h * DH + d4));
        }
      }
      __syncthreads();
      float4 kreg[16];
#pragma unroll
      for (int d4 = 0; d4 < 16; ++d4) kreg[d4] = *(const float4*)&Ks[lane][d4 * 4];
      float p[4];
#pragma unroll
      for (int r = 0; r < 4; ++r) {
        float s = 0.f;
#pragma unroll
        for (int d4 = 0; d4 < 16; ++d4) {
          float4 q = *(const float4*)&Qs[r0 + r][d4 * 4];
          s += q.x * kreg[d4].x + q.y * kreg[d4].y + q.z * kreg[d4].z + q.w * kreg[d4].w;
        }
        p[r] = (lane < tc && r0 + r < rows) ? __expf(s * scale) : 0.f;
        lsum[r] += p[r];
      }
      float4 p4; p4.x = p[0]; p4.y = p[1]; p4.z = p[2]; p4.w = p[3];
      *(float4*)&Ps[w][lane][0] = p4;
      __asm__ volatile("s_waitcnt lgkmcnt(0)" ::: "memory");  // wave-private RAW
      for (int j = 0; j < tc; ++j) {
        const float v = Vs[j][lane];
        float4 pj = *(const float4*)&Ps[w][j][0];
        accv[0] += pj.x * v; accv[1] += pj.y * v;
        accv[2] += pj.z * v; accv[3] += pj.w * v;
      }
    }
#pragma unroll
    for (int off = 32; off; off >>= 1)
#pragma unroll
      for (int r = 0; r < 4; ++r) lsum[r] += __shfl_xor(lsum[r], off);
#pragma unroll
    for (int r = 0; r < 4; ++r)
      if (r0 + r < rows)
        ao[(size_t)(row0 + r0 + r) * HIDDEN + h * DH + lane] = f2bf(accv[r] / lsum[r]);
  }
}

// Launch 3: out = ao @ w_out^T + b_out + query  (bf16 A, fp32 out + residual).
__global__ __launch_bounds__(256) void k_out(const unsigned short* __restrict__ ao,
                                             const float* __restrict__ w_out,
                                             const float* __restrict__ b_out,
                                             const float* __restrict__ query,
                                             float* __restrict__ out) {
  __shared__ unsigned short As[64 * 72];
  __shared__ unsigned short Ws[64 * 72];
  gemm_tile<true, false, true>(ao, w_out, b_out, query, out, 256,
                               blockIdx.x * 64, blockIdx.y * 64, As, Ws);
}

extern "C" void kernel_launch(void* const* d_in, const int* in_sizes, int n_in,
                              void* d_out, int out_size, void* d_ws, size_t ws_size,
                              hipStream_t stream) {
  const float* query  = (const float*)d_in[0];
  const float* key    = (const float*)d_in[1];
  const float* value  = (const float*)d_in[2];
  const int*   gidx   = (const int*)d_in[3];
  const float* w_edge = (const float*)d_in[4];
  const float* b_edge = (const float*)d_in[5];
  const float* w_in   = (const float*)d_in[6];
  const float* b_in   = (const float*)d_in[7];
  const float* w_out  = (const float*)d_in[8];
  const float* b_out  = (const float*)d_in[9];
  float* out = (float*)d_out;

  // workspace layout (~8.1 MiB)
  int* segStart = (int*)d_ws;                              // 128 ints
  unsigned short* Qh = (unsigned short*)((char*)d_ws + 512);
  unsigned short* Kh = Qh + (size_t)N_EDGES * HIDDEN;
  unsigned short* Vh = Kh + (size_t)N_EDGES * HIDDEN;
  unsigned short* ao = Vh + (size_t)N_EDGES * HIDDEN;

  k_qkv<<<dim3(385), 256, 0, stream>>>(query, key, value, w_in, b_in,
                                       w_edge, b_edge, gidx, Qh, Kh, Vh, segStart);
  attn_segment<<<dim3(NUM_GRAPHS, NUM_HEADS, 8), 256, 0, stream>>>(Qh, Kh, Vh,
                                                                   segStart, ao);
  k_out<<<dim3(64, 4), 256, 0, stream>>>(ao, w_out, b_out, query, out);
}

// Round 6
// 120.559 us; speedup vs baseline: 1.0277x; 1.0277x over previous
//
#include <hip/hip_runtime.h>

#define N_EDGES 4096
#define HIDDEN  256
#define EDGE_DIM 128
#define NUM_HEADS 4
#define NUM_GRAPHS 64
#define DH 64   // head dim

typedef __attribute__((ext_vector_type(8))) short short8;
typedef __attribute__((ext_vector_type(4))) float f32x4;

__device__ __forceinline__ unsigned short f2bf(float f) {
  unsigned u = __builtin_bit_cast(unsigned, f);
  u += 0x7FFF + ((u >> 16) & 1);          // RNE
  return (unsigned short)(u >> 16);
}
__device__ __forceinline__ float bf2f(unsigned short u) {
  return __builtin_bit_cast(float, (unsigned)u << 16);
}
__device__ __forceinline__ short8 cvt8(float4 x, float4 y) {
  short8 v;
  v[0] = (short)f2bf(x.x); v[1] = (short)f2bf(x.y);
  v[2] = (short)f2bf(x.z); v[3] = (short)f2bf(x.w);
  v[4] = (short)f2bf(y.x); v[5] = (short)f2bf(y.y);
  v[6] = (short)f2bf(y.z); v[7] = (short)f2bf(y.w);
  return v;
}
__device__ __forceinline__ float4 us4f(ushort4 v) {
  float4 f;
  f.x = bf2f(v.x); f.y = bf2f(v.y); f.z = bf2f(v.z); f.w = bf2f(v.w);
  return f;
}

__device__ __forceinline__ int lbound(const int* __restrict__ a, int n, int v) {
  int lo = 0, hi = n;
  while (lo < hi) { int mid = (lo + hi) >> 1; if (a[mid] < v) lo = mid + 1; else hi = mid; }
  return lo;
}

// MFMA GEMM tile: 64x64 out, 256 thr = 4 waves, BK=64 (round-4-proven).
// A fp32/bf16 [M x K]; W fp32/bf16 [N x K] row-major.
// OUTF32: C = fp32(acc+bias+res) stride HIDDEN; else C = bf16(acc+bias).
template<bool ABF, bool WBF, bool OUTF32>
__device__ __forceinline__ void gemm_tile(const void* Ap, const void* Wp,
                                          const float* __restrict__ bias,
                                          const float* __restrict__ res,
                                          void* Cp, const int K,
                                          const int m0, const int n0,
                                          unsigned short* As, unsigned short* Ws) {
  const int t = threadIdx.x;
  const int r = t >> 2, kg = t & 3;           // row 0..63, 16-elem k-group 0..3
  const int lane = t & 63, w = t >> 6;
  const int quad = lane >> 4, l16 = lane & 15;
  const int wm = (w >> 1) * 32, wn = (w & 1) * 32;
  f32x4 acc[2][2] = {};
  const float*          pa32 = (const float*)Ap          + (size_t)(m0 + r) * K + kg * 16;
  const unsigned short* pa16 = (const unsigned short*)Ap + (size_t)(m0 + r) * K + kg * 16;
  const float*          pw32 = (const float*)Wp          + (size_t)(n0 + r) * K + kg * 16;
  const unsigned short* pw16 = (const unsigned short*)Wp + (size_t)(n0 + r) * K + kg * 16;
  float4 a0, a1, a2, a3, w0, w1, w2, w3;
  short8 a16a, a16b, w16a, w16b;
  if (ABF) { a16a = *(const short8*)pa16; a16b = *(const short8*)(pa16 + 8); }
  else { a0 = *(const float4*)pa32;       a1 = *(const float4*)(pa32 + 4);
         a2 = *(const float4*)(pa32 + 8); a3 = *(const float4*)(pa32 + 12); }
  if (WBF) { w16a = *(const short8*)pw16; w16b = *(const short8*)(pw16 + 8); }
  else { w0 = *(const float4*)pw32;       w1 = *(const float4*)(pw32 + 4);
         w2 = *(const float4*)(pw32 + 8); w3 = *(const float4*)(pw32 + 12); }
  for (int kc = 0; kc < K; kc += 64) {
    short8 na16a, na16b, nw16a, nw16b;
    float4 na0, na1, na2, na3, nw0, nw1, nw2, nw3;
    if (kc + 64 < K) {
      if (ABF) { na16a = *(const short8*)(pa16 + kc + 64);
                 na16b = *(const short8*)(pa16 + kc + 72); }
      else { na0 = *(const float4*)(pa32 + kc + 64); na1 = *(const float4*)(pa32 + kc + 68);
             na2 = *(const float4*)(pa32 + kc + 72); na3 = *(const float4*)(pa32 + kc + 76); }
      if (WBF) { nw16a = *(const short8*)(pw16 + kc + 64);
                 nw16b = *(const short8*)(pw16 + kc + 72); }
      else { nw0 = *(const float4*)(pw32 + kc + 64); nw1 = *(const float4*)(pw32 + kc + 68);
             nw2 = *(const float4*)(pw32 + kc + 72); nw3 = *(const float4*)(pw32 + kc + 76); }
    }
    __syncthreads();
    *(short8*)&As[r * 72 + kg * 16]     = ABF ? a16a : cvt8(a0, a1);
    *(short8*)&As[r * 72 + kg * 16 + 8] = ABF ? a16b : cvt8(a2, a3);
    *(short8*)&Ws[r * 72 + kg * 16]     = WBF ? w16a : cvt8(w0, w1);
    *(short8*)&Ws[r * 72 + kg * 16 + 8] = WBF ? w16b : cvt8(w2, w3);
    __syncthreads();
#pragma unroll
    for (int ks = 0; ks < 2; ++ks) {
      short8 af0 = *(const short8*)&As[(wm + l16) * 72 + ks * 32 + quad * 8];
      short8 af1 = *(const short8*)&As[(wm + 16 + l16) * 72 + ks * 32 + quad * 8];
      short8 bq0 = *(const short8*)&Ws[(wn + l16) * 72 + ks * 32 + quad * 8];
      short8 bq1 = *(const short8*)&Ws[(wn + 16 + l16) * 72 + ks * 32 + quad * 8];
      acc[0][0] = __builtin_amdgcn_mfma_f32_16x16x32_bf16(af0, bq0, acc[0][0], 0, 0, 0);
      acc[0][1] = __builtin_amdgcn_mfma_f32_16x16x32_bf16(af0, bq1, acc[0][1], 0, 0, 0);
      acc[1][0] = __builtin_amdgcn_mfma_f32_16x16x32_bf16(af1, bq0, acc[1][0], 0, 0, 0);
      acc[1][1] = __builtin_amdgcn_mfma_f32_16x16x32_bf16(af1, bq1, acc[1][1], 0, 0, 0);
    }
    a16a = na16a; a16b = na16b; a0 = na0; a1 = na1; a2 = na2; a3 = na3;
    w16a = nw16a; w16b = nw16b; w0 = nw0; w1 = nw1; w2 = nw2; w3 = nw3;
  }
#pragma unroll
  for (int j = 0; j < 2; ++j) {
    const int col = n0 + wn + j * 16 + l16;
    const float bj = bias[col];
#pragma unroll
    for (int i = 0; i < 2; ++i)
#pragma unroll
      for (int reg = 0; reg < 4; ++reg) {
        const int row = m0 + wm + i * 16 + quad * 4 + reg;
        const size_t idx = (size_t)row * HIDDEN + col;
        float v = acc[i][j][reg] + bj;
        if (OUTF32) ((float*)Cp)[idx] = v + res[idx];
        else        ((unsigned short*)Cp)[idx] = f2bf(v);
      }
  }
}

// Fused-weight tile (round-4 verbatim, verified): Wf_sel[n0:+64, k0:+64] =
// bf16(Wp @ w_edge); k0==0 tiles also emit bf_sel[n] = Wp[n,:]@b_edge + bp[n].
__device__ __forceinline__ void wf_part(int bb, const float* __restrict__ w_in,
                                        const float* __restrict__ b_in,
                                        const float* __restrict__ w_edge,
                                        const float* __restrict__ b_edge,
                                        unsigned short* __restrict__ Wfk,
                                        unsigned short* __restrict__ Wfv,
                                        float* __restrict__ bfk, float* __restrict__ bfv,
                                        unsigned short* As, unsigned short* Bs) {
  const int sel = bb >> 3;            // 0 = K-weight, 1 = V-weight
  const int tt  = bb & 7;
  const int n0  = (tt >> 1) * 64;
  const int k0  = (tt & 1) * 64;
  const float* Wp = w_in + (size_t)(256 + 256 * sel) * HIDDEN;
  const float* bp = b_in + 256 + 256 * sel;
  unsigned short* Wf = sel ? Wfv : Wfk;
  float* bf = sel ? bfv : bfk;
  const int t = threadIdx.x;
  const int r = t >> 2, kg = t & 3;
  const int lane = t & 63, w = t >> 6;
  const int quad = lane >> 4, l16 = lane & 15;
  const int wm = (w >> 1) * 32, wn = (w & 1) * 32;
  if (k0 == 0) {
    float s = 0.f;
    const float* wrow = Wp + (size_t)(n0 + r) * HIDDEN + kg * 64;
    const float* be = b_edge + kg * 64;
#pragma unroll
    for (int j = 0; j < 64; j += 4) {
      float4 a = *(const float4*)(wrow + j);
      float4 b = *(const float4*)(be + j);
      s += a.x * b.x + a.y * b.y + a.z * b.z + a.w * b.w;
    }
    s += __shfl_xor(s, 1); s += __shfl_xor(s, 2);
    if (kg == 0) bf[n0 + r] = s + bp[n0 + r];
  }
  f32x4 facc[2][2] = {};
  for (int j0 = 0; j0 < HIDDEN; j0 += 32) {
    __syncthreads();
    { const float* p = Wp + (size_t)(n0 + r) * HIDDEN + j0 + kg * 8;
      float4 x0 = *(const float4*)p, x1 = *(const float4*)(p + 4);
      *(short8*)&As[r * 40 + kg * 8] = cvt8(x0, x1); }
    { const int j = t >> 3, k8 = (t & 7) * 8;   // Bs[k][j] = w_edge[j0+j][k0+k]
      const float* p = w_edge + (size_t)(j0 + j) * EDGE_DIM + k0 + k8;
      float4 b0 = *(const float4*)p, b1 = *(const float4*)(p + 4);
      float bv[8] = {b0.x, b0.y, b0.z, b0.w, b1.x, b1.y, b1.z, b1.w};
#pragma unroll
      for (int i = 0; i < 8; ++i) Bs[(k8 + i) * 40 + j] = f2bf(bv[i]); }
    __syncthreads();
    short8 af0 = *(const short8*)&As[(wm + l16) * 40 + quad * 8];
    short8 af1 = *(const short8*)&As[(wm + 16 + l16) * 40 + quad * 8];
    short8 bq0 = *(const short8*)&Bs[(wn + l16) * 40 + quad * 8];
    short8 bq1 = *(const short8*)&Bs[(wn + 16 + l16) * 40 + quad * 8];
    facc[0][0] = __builtin_amdgcn_mfma_f32_16x16x32_bf16(af0, bq0, facc[0][0], 0, 0, 0);
    facc[0][1] = __builtin_amdgcn_mfma_f32_16x16x32_bf16(af0, bq1, facc[0][1], 0, 0, 0);
    facc[1][0] = __builtin_amdgcn_mfma_f32_16x16x32_bf16(af1, bq0, facc[1][0], 0, 0, 0);
    facc[1][1] = __builtin_amdgcn_mfma_f32_16x16x32_bf16(af1, bq1, facc[1][1], 0, 0, 0);
  }
#pragma unroll
  for (int jj = 0; jj < 2; ++jj)
#pragma unroll
    for (int ii = 0; ii < 2; ++ii)
#pragma unroll
      for (int reg = 0; reg < 4; ++reg) {
        const int n = wm + ii * 16 + quad * 4 + reg;
        const int k = wn + jj * 16 + l16;
        Wf[(size_t)(n0 + n) * EDGE_DIM + k0 + k] = f2bf(facc[ii][jj][reg]);
      }
}

// LDS union: Q-path GEMM (BK64, 18.4 KB) vs Wf path (BK32, 10.2 KB).
union SharedL1 {
  struct { unsigned short As[64 * 72]; unsigned short Ws[64 * 72]; } g;
  struct { unsigned short As[64 * 40]; unsigned short Bs[64 * 40]; } w;
};

// Launch 1: b<256 Qh tiles (K=256, independent of Wf); b<272 Wf tiles;
// b==272 segStart. Wf latency hides under the 256 Q-tile blocks.
__global__ __launch_bounds__(256) void k_q_wf(const float* __restrict__ query,
                                              const float* __restrict__ w_in,
                                              const float* __restrict__ b_in,
                                              const float* __restrict__ w_edge,
                                              const float* __restrict__ b_edge,
                                              const int* __restrict__ gidx,
                                              unsigned short* Qh,
                                              unsigned short* Wfk, unsigned short* Wfv,
                                              float* bfk, float* bfv, int* segStart) {
  __shared__ SharedL1 sh;
  const int b = blockIdx.x;
  if (b < 256) {
    gemm_tile<false, false, false>(query, w_in, b_in, nullptr, Qh, 256,
                                   (b & 63) * 64, (b >> 6) * 64, sh.g.As, sh.g.Ws);
  } else if (b < 272) {
    wf_part(b - 256, w_in, b_in, w_edge, b_edge, Wfk, Wfv, bfk, bfv, sh.w.As, sh.w.Bs);
  } else if (threadIdx.x <= NUM_GRAPHS) {
    segStart[threadIdx.x] = lbound(gidx, N_EDGES, threadIdx.x);
  }
}

// Launch 2: Kh/Vh = key/value @ Wf^T + bf. K=128 -> only 2 BK64 iterations.
__global__ __launch_bounds__(256) void k_kv(const float* __restrict__ key,
                                            const float* __restrict__ value,
                                            const unsigned short* __restrict__ Wfk,
                                            const unsigned short* __restrict__ Wfv,
                                            const float* __restrict__ bfk,
                                            const float* __restrict__ bfv,
                                            unsigned short* Kh, unsigned short* Vh) {
  __shared__ unsigned short As[64 * 72];
  __shared__ unsigned short Ws[64 * 72];
  const int m0 = blockIdx.x * 64, n0 = blockIdx.y * 64;
  if (blockIdx.z == 0)
    gemm_tile<false, true, false>(key, Wfk, bfk, nullptr, Kh, 128, m0, n0, As, Ws);
  else
    gemm_tile<false, true, false>(value, Wfv, bfv, nullptr, Vh, 128, m0, n0, As, Ws);
}

// Launch 3: segment attention (round-0-proven structure, verbatim).
__global__ __launch_bounds__(256) void attn_segment(const unsigned short* __restrict__ Qh,
                                                    const unsigned short* __restrict__ Kh,
                                                    const unsigned short* __restrict__ Vh,
                                                    const int* __restrict__ segStart,
                                                    unsigned short* __restrict__ ao) {
  const int graph = blockIdx.x, h = blockIdx.y, zg = blockIdx.z;
  const int segLo = segStart[graph];
  const int segHi = segStart[graph + 1];
  const int segLen = segHi - segLo;
  const int t = threadIdx.x, lane = t & 63, w = t >> 6;
  __shared__ float Qs[16][68], Ks[64][68], Vs[64][68];
  __shared__ float Ps[4][64][4];
  const float scale = 0.125f;           // 1/sqrt(64)
  const int r0 = w * 4;

  for (int chunk = zg; chunk * 16 < segLen; chunk += 8) {
    const int row0 = segLo + chunk * 16;
    const int rows = min(16, segHi - row0);
    __syncthreads();                    // prev chunk fully consumed
    { int r = t >> 4, d4 = (t & 15) * 4;
      if (r < rows)
        *(float4*)&Qs[r][d4] =
            us4f(*(const ushort4*)(Qh + (size_t)(row0 + r) * HIDDEN + h * DH + d4)); }

    float accv[4] = {0.f, 0.f, 0.f, 0.f}, lsum[4] = {0.f, 0.f, 0.f, 0.f};

    for (int c0 = segLo; c0 < segHi; c0 += 64) {
      const int tc = min(64, segHi - c0);
      __syncthreads();                  // Qs staged / prev tile reads done
#pragma unroll
      for (int it = 0; it < 4; ++it) {
        int s = t + it * 256; int j = s >> 4; int d4 = (s & 15) * 4;
        if (j < tc) {
          *(float4*)&Ks[j][d4] =
              us4f(*(const ushort4*)(Kh + (size_t)(c0 + j) * HIDDEN + h * DH + d4));
          *(float4*)&Vs[j][d4] =
              us4f(*(const ushort4*)(Vh + (size_t)(c0 + j) * HIDDEN + h * DH + d4));
        }
      }
      __syncthreads();
      float4 kreg[16];
#pragma unroll
      for (int d4 = 0; d4 < 16; ++d4) kreg[d4] = *(const float4*)&Ks[lane][d4 * 4];
      float p[4];
#pragma unroll
      for (int r = 0; r < 4; ++r) {
        float s = 0.f;
#pragma unroll
        for (int d4 = 0; d4 < 16; ++d4) {
          float4 q = *(const float4*)&Qs[r0 + r][d4 * 4];
          s += q.x * kreg[d4].x + q.y * kreg[d4].y + q.z * kreg[d4].z + q.w * kreg[d4].w;
        }
        p[r] = (lane < tc && r0 + r < rows) ? __expf(s * scale) : 0.f;
        lsum[r] += p[r];
      }
      float4 p4; p4.x = p[0]; p4.y = p[1]; p4.z = p[2]; p4.w = p[3];
      *(float4*)&Ps[w][lane][0] = p4;
      __asm__ volatile("s_waitcnt lgkmcnt(0)" ::: "memory");  // wave-private RAW
      for (int j = 0; j < tc; ++j) {
        const float v = Vs[j][lane];
        float4 pj = *(const float4*)&Ps[w][j][0];
        accv[0] += pj.x * v; accv[1] += pj.y * v;
        accv[2] += pj.z * v; accv[3] += pj.w * v;
      }
    }
#pragma unroll
    for (int off = 32; off; off >>= 1)
#pragma unroll
      for (int r = 0; r < 4; ++r) lsum[r] += __shfl_xor(lsum[r], off);
#pragma unroll
    for (int r = 0; r < 4; ++r)
      if (r0 + r < rows)
        ao[(size_t)(row0 + r0 + r) * HIDDEN + h * DH + lane] = f2bf(accv[r] / lsum[r]);
  }
}

// Launch 4: out = ao @ w_out^T + b_out + query  (bf16 A, fp32 out + residual).
__global__ __launch_bounds__(256) void k_out(const unsigned short* __restrict__ ao,
                                             const float* __restrict__ w_out,
                                             const float* __restrict__ b_out,
                                             const float* __restrict__ query,
                                             float* __restrict__ out) {
  __shared__ unsigned short As[64 * 72];
  __shared__ unsigned short Ws[64 * 72];
  gemm_tile<true, false, true>(ao, w_out, b_out, query, out, 256,
                               blockIdx.x * 64, blockIdx.y * 64, As, Ws);
}

extern "C" void kernel_launch(void* const* d_in, const int* in_sizes, int n_in,
                              void* d_out, int out_size, void* d_ws, size_t ws_size,
                              hipStream_t stream) {
  const float* query  = (const float*)d_in[0];
  const float* key    = (const float*)d_in[1];
  const float* value  = (const float*)d_in[2];
  const int*   gidx   = (const int*)d_in[3];
  const float* w_edge = (const float*)d_in[4];
  const float* b_edge = (const float*)d_in[5];
  const float* w_in   = (const float*)d_in[6];
  const float* b_in   = (const float*)d_in[7];
  const float* w_out  = (const float*)d_in[8];
  const float* b_out  = (const float*)d_in[9];
  float* out = (float*)d_out;

  // workspace layout (~8.2 MiB)
  int* segStart = (int*)d_ws;                              // 128 ints
  unsigned short* Qh  = (unsigned short*)((char*)d_ws + 512);
  unsigned short* Kh  = Qh + (size_t)N_EDGES * HIDDEN;
  unsigned short* Vh  = Kh + (size_t)N_EDGES * HIDDEN;
  unsigned short* ao  = Vh + (size_t)N_EDGES * HIDDEN;
  unsigned short* Wfk = ao + (size_t)N_EDGES * HIDDEN;
  unsigned short* Wfv = Wfk + 256 * EDGE_DIM;
  float* bfk = (float*)(Wfv + 256 * EDGE_DIM);
  float* bfv = bfk + 256;

  k_q_wf<<<dim3(273), 256, 0, stream>>>(query, w_in, b_in, w_edge, b_edge, gidx,
                                        Qh, Wfk, Wfv, bfk, bfv, segStart);
  k_kv<<<dim3(64, 4, 2), 256, 0, stream>>>(key, value, Wfk, Wfv, bfk, bfv, Kh, Vh);
  attn_segment<<<dim3(NUM_GRAPHS, NUM_HEADS, 8), 256, 0, stream>>>(Qh, Kh, Vh,
                                                                   segStart, ao);
  k_out<<<dim3(64, 4), 256, 0, stream>>>(ao, w_out, b_out, query, out);
}